// Round 1
// baseline (304.244 us; speedup 1.0000x reference)
//
#include <hip/hip_runtime.h>
#include <stdint.h>

typedef unsigned short u16;
typedef __bf16 bf16x8 __attribute__((ext_vector_type(8)));
typedef float f32x4 __attribute__((ext_vector_type(4)));

#define D_MODEL 1024
#define NH 16
#define DHEAD 64
#define BB 4
#define SS 2048
#define MM (BB*SS)   // 8192 rows

__device__ __forceinline__ u16 f2bf(float f) {
    unsigned int u = __float_as_uint(f);
    u += 0x7fffu + ((u >> 16) & 1u);   // round-to-nearest-even
    return (u16)(u >> 16);
}
__device__ __forceinline__ float bf2f(u16 s) {
    return __uint_as_float(((unsigned int)s) << 16);
}

union U8 {
    uint4 q;
    u16   v[8];
    bf16x8 f;
};

// ---------------------------------------------------------------- cvt f32->bf16
__global__ __launch_bounds__(256) void cvt_kernel(const float* __restrict__ src,
                                                  u16* __restrict__ dst, int n4) {
    int i = blockIdx.x * 256 + threadIdx.x;
    if (i < n4) {
        float4 f = ((const float4*)src)[i];
        u16 o[4] = { f2bf(f.x), f2bf(f.y), f2bf(f.z), f2bf(f.w) };
        ((uint2*)dst)[i] = *(const uint2*)o;
    }
}

// ---------------------------------------------------------------- GEMM1: qkv = x @ Wqkv^T, permuted bf16 out
__global__ __launch_bounds__(256) void gemm_qkv_kernel(const u16* __restrict__ A,   // [8192][1024]
                                                       const u16* __restrict__ Bt,  // [1024][1024] (N,K)
                                                       u16* __restrict__ Cq)        // [B][H][S][64]
{
    __shared__ __align__(16) u16 As[128*32];
    __shared__ __align__(16) u16 Bs[128*32];

    const int tid  = threadIdx.x;
    const int wave = tid >> 6;
    const int lane = tid & 63;
    const int quad = lane >> 4;
    const int l16  = lane & 15;
    const int bm = blockIdx.x >> 3;
    const int bn = blockIdx.x & 7;
    const int wm = wave >> 1, wn = wave & 1;

    f32x4 acc[4][4] = {};

    const int c0 = tid,        r0 = c0 >> 2, kc0 = (c0 & 3) * 8;
    const int c1 = tid + 256,  r1 = c1 >> 2, kc1 = (c1 & 3) * 8;

    const u16* Ab = A  + (size_t)(bm * 128) * D_MODEL;
    const u16* Bb = Bt + (size_t)(bn * 128) * D_MODEL;

    for (int k0 = 0; k0 < D_MODEL; k0 += 32) {
        __builtin_amdgcn_global_load_lds(
            (__attribute__((address_space(1))) void*)(Ab + (size_t)r0 * D_MODEL + k0 + kc0),
            (__attribute__((address_space(3))) void*)(As + c0 * 8), 16, 0, 0);
        __builtin_amdgcn_global_load_lds(
            (__attribute__((address_space(1))) void*)(Ab + (size_t)r1 * D_MODEL + k0 + kc1),
            (__attribute__((address_space(3))) void*)(As + c1 * 8), 16, 0, 0);
        __builtin_amdgcn_global_load_lds(
            (__attribute__((address_space(1))) void*)(Bb + (size_t)r0 * D_MODEL + k0 + kc0),
            (__attribute__((address_space(3))) void*)(Bs + c0 * 8), 16, 0, 0);
        __builtin_amdgcn_global_load_lds(
            (__attribute__((address_space(1))) void*)(Bb + (size_t)r1 * D_MODEL + k0 + kc1),
            (__attribute__((address_space(3))) void*)(Bs + c1 * 8), 16, 0, 0);
        __syncthreads();

        bf16x8 af[4], bfr[4];
#pragma unroll
        for (int t = 0; t < 4; ++t)
            af[t] = *(const bf16x8*)(const void*)(As + (wm*64 + t*16 + l16)*32 + quad*8);
#pragma unroll
        for (int t = 0; t < 4; ++t)
            bfr[t] = *(const bf16x8*)(const void*)(Bs + (wn*64 + t*16 + l16)*32 + quad*8);
#pragma unroll
        for (int i = 0; i < 4; ++i)
#pragma unroll
            for (int j = 0; j < 4; ++j)
                acc[i][j] = __builtin_amdgcn_mfma_f32_16x16x32_bf16(af[i], bfr[j], acc[i][j], 0, 0, 0);
        __syncthreads();
    }

    const int rowbase = bm*128 + wm*64;
    const int colbase = bn*128 + wn*64;
#pragma unroll
    for (int j = 0; j < 4; ++j) {
        const int col = colbase + j*16 + l16;
        const int h = col >> 6, dh = col & 63;
#pragma unroll
        for (int i = 0; i < 4; ++i) {
#pragma unroll
            for (int r = 0; r < 4; ++r) {
                const int row = rowbase + i*16 + quad*4 + r;
                const int b = row >> 11, s = row & (SS - 1);
                Cq[(((size_t)(b*NH + h))*SS + s)*DHEAD + dh] = f2bf(acc[i][j][r]);
            }
        }
    }
}

// ---------------------------------------------------------------- GEMM2: out = attn @ Wout^T + bias (fp32 out)
__global__ __launch_bounds__(256) void gemm_out_kernel(const u16* __restrict__ A,   // [8192][1024]
                                                       const u16* __restrict__ Bt,  // [1024][1024]
                                                       const float* __restrict__ Bo,
                                                       float* __restrict__ Out)     // [8192][1024]
{
    __shared__ __align__(16) u16 As[128*32];
    __shared__ __align__(16) u16 Bs[128*32];

    const int tid  = threadIdx.x;
    const int wave = tid >> 6;
    const int lane = tid & 63;
    const int quad = lane >> 4;
    const int l16  = lane & 15;
    const int bm = blockIdx.x >> 3;
    const int bn = blockIdx.x & 7;
    const int wm = wave >> 1, wn = wave & 1;

    f32x4 acc[4][4] = {};

    const int c0 = tid,        r0 = c0 >> 2, kc0 = (c0 & 3) * 8;
    const int c1 = tid + 256,  r1 = c1 >> 2, kc1 = (c1 & 3) * 8;

    const u16* Ab = A  + (size_t)(bm * 128) * D_MODEL;
    const u16* Bb = Bt + (size_t)(bn * 128) * D_MODEL;

    for (int k0 = 0; k0 < D_MODEL; k0 += 32) {
        __builtin_amdgcn_global_load_lds(
            (__attribute__((address_space(1))) void*)(Ab + (size_t)r0 * D_MODEL + k0 + kc0),
            (__attribute__((address_space(3))) void*)(As + c0 * 8), 16, 0, 0);
        __builtin_amdgcn_global_load_lds(
            (__attribute__((address_space(1))) void*)(Ab + (size_t)r1 * D_MODEL + k0 + kc1),
            (__attribute__((address_space(3))) void*)(As + c1 * 8), 16, 0, 0);
        __builtin_amdgcn_global_load_lds(
            (__attribute__((address_space(1))) void*)(Bb + (size_t)r0 * D_MODEL + k0 + kc0),
            (__attribute__((address_space(3))) void*)(Bs + c0 * 8), 16, 0, 0);
        __builtin_amdgcn_global_load_lds(
            (__attribute__((address_space(1))) void*)(Bb + (size_t)r1 * D_MODEL + k0 + kc1),
            (__attribute__((address_space(3))) void*)(Bs + c1 * 8), 16, 0, 0);
        __syncthreads();

        bf16x8 af[4], bfr[4];
#pragma unroll
        for (int t = 0; t < 4; ++t)
            af[t] = *(const bf16x8*)(const void*)(As + (wm*64 + t*16 + l16)*32 + quad*8);
#pragma unroll
        for (int t = 0; t < 4; ++t)
            bfr[t] = *(const bf16x8*)(const void*)(Bs + (wn*64 + t*16 + l16)*32 + quad*8);
#pragma unroll
        for (int i = 0; i < 4; ++i)
#pragma unroll
            for (int j = 0; j < 4; ++j)
                acc[i][j] = __builtin_amdgcn_mfma_f32_16x16x32_bf16(af[i], bfr[j], acc[i][j], 0, 0, 0);
        __syncthreads();
    }

    const int rowbase = bm*128 + wm*64;
    const int colbase = bn*128 + wn*64;
#pragma unroll
    for (int j = 0; j < 4; ++j) {
        const int col = colbase + j*16 + l16;
        const float bias = Bo[col];
#pragma unroll
        for (int i = 0; i < 4; ++i) {
#pragma unroll
            for (int r = 0; r < 4; ++r) {
                const int row = rowbase + i*16 + quad*4 + r;
                Out[(size_t)row * D_MODEL + col] = acc[i][j][r] + bias;
            }
        }
    }
}

// ---------------------------------------------------------------- attention (Q=K=V), no-max online softmax
__global__ __launch_bounds__(256) void attn_kernel(const u16* __restrict__ qkv,  // [B*H][2048][64]
                                                   u16* __restrict__ outb)       // [B][S][1024]
{
    __shared__ __align__(16) u16 Ks[32*72];     // keys x dh, stride 72
    __shared__ __align__(16) u16 Vt[64*40];     // dh x keys, stride 40
    __shared__ __align__(16) u16 Ps[4*32*40];   // per-wave P, stride 40

    const int tid  = threadIdx.x;
    const int wave = tid >> 6;
    const int lane = tid & 63;
    const int quad = lane >> 4;
    const int l16  = lane & 15;

    const int bh   = blockIdx.x >> 4;   // b*16+h
    const int qblk = blockIdx.x & 15;
    const u16* base = qkv + (size_t)bh * SS * DHEAD;
    const int qbase = qblk * 128 + wave * 32;

    const float qscale = 0.125f * 1.4426950408889634f; // fold 1/sqrt(64) and log2(e)

    // preload scaled Q fragments (A-operand layout)
    bf16x8 aq[2][2];
#pragma unroll
    for (int mt = 0; mt < 2; ++mt)
#pragma unroll
        for (int ks = 0; ks < 2; ++ks) {
            U8 raw; raw.q = *(const uint4*)(base + (size_t)(qbase + mt*16 + l16)*DHEAD + ks*32 + quad*8);
            U8 w;
#pragma unroll
            for (int j = 0; j < 8; ++j) w.v[j] = f2bf(bf2f(raw.v[j]) * qscale);
            aq[mt][ks] = w.f;
        }

    bf16x8 ones;
#pragma unroll
    for (int j = 0; j < 8; ++j) ones[j] = (__bf16)1.0f;

    f32x4 o[2][4] = {};
    f32x4 lsum[2] = {};

    u16* Pw = Ps + wave * (32*40);
    const int skey = tid >> 3, sdh = (tid & 7) * 8;

    for (int kt = 0; kt < SS/32; ++kt) {
        // stage K tile and transposed V tile
        {
            U8 raw; raw.q = *(const uint4*)(base + (size_t)(kt*32 + skey)*DHEAD + sdh);
            *(uint4*)(Ks + skey*72 + sdh) = raw.q;
#pragma unroll
            for (int j = 0; j < 8; ++j) Vt[(sdh + j)*40 + skey] = raw.v[j];
        }
        __syncthreads();

        // S = Q' K^T  (already in exp2 domain)
        f32x4 s[2][2] = {};
#pragma unroll
        for (int ks = 0; ks < 2; ++ks) {
            bf16x8 bk[2];
#pragma unroll
            for (int nt = 0; nt < 2; ++nt)
                bk[nt] = *(const bf16x8*)(const void*)(Ks + (nt*16 + l16)*72 + ks*32 + quad*8);
#pragma unroll
            for (int mt = 0; mt < 2; ++mt)
#pragma unroll
                for (int nt = 0; nt < 2; ++nt)
                    s[mt][nt] = __builtin_amdgcn_mfma_f32_16x16x32_bf16(aq[mt][ks], bk[nt], s[mt][nt], 0, 0, 0);
        }

        // P = exp2(S), stash in wave-private LDS as A-operand source
#pragma unroll
        for (int mt = 0; mt < 2; ++mt)
#pragma unroll
            for (int nt = 0; nt < 2; ++nt)
#pragma unroll
                for (int r = 0; r < 4; ++r) {
                    float p = __builtin_amdgcn_exp2f(s[mt][nt][r]);
                    Pw[(mt*16 + quad*4 + r)*40 + nt*16 + l16] = f2bf(p);
                }

        bf16x8 ap[2];
#pragma unroll
        for (int mt = 0; mt < 2; ++mt)
            ap[mt] = *(const bf16x8*)(const void*)(Pw + (mt*16 + l16)*40 + quad*8);

        bf16x8 bv[4];
#pragma unroll
        for (int nt = 0; nt < 4; ++nt)
            bv[nt] = *(const bf16x8*)(const void*)(Vt + (nt*16 + l16)*40 + quad*8);

#pragma unroll
        for (int mt = 0; mt < 2; ++mt) {
            lsum[mt] = __builtin_amdgcn_mfma_f32_16x16x32_bf16(ap[mt], ones, lsum[mt], 0, 0, 0);
#pragma unroll
            for (int nt = 0; nt < 4; ++nt)
                o[mt][nt] = __builtin_amdgcn_mfma_f32_16x16x32_bf16(ap[mt], bv[nt], o[mt][nt], 0, 0, 0);
        }
        __syncthreads();
    }

    const int b = bh >> 4, h = bh & 15;
#pragma unroll
    for (int mt = 0; mt < 2; ++mt) {
        float inv[4];
#pragma unroll
        for (int r = 0; r < 4; ++r) inv[r] = 1.0f / lsum[mt][r];
#pragma unroll
        for (int nt = 0; nt < 4; ++nt) {
            const int col = h*64 + nt*16 + l16;
#pragma unroll
            for (int r = 0; r < 4; ++r) {
                const int srow = qbase + mt*16 + quad*4 + r;
                outb[((size_t)(b*SS + srow))*D_MODEL + col] = f2bf(o[mt][nt][r] * inv[r]);
            }
        }
    }
}

// ---------------------------------------------------------------- launcher
extern "C" void kernel_launch(void* const* d_in, const int* in_sizes, int n_in,
                              void* d_out, int out_size, void* d_ws, size_t ws_size,
                              hipStream_t stream)
{
    (void)in_sizes; (void)n_in; (void)out_size; (void)ws_size;
    const float* x  = (const float*)d_in[0];
    const float* wq = (const float*)d_in[1];
    const float* wo = (const float*)d_in[2];
    const float* bo = (const float*)d_in[3];

    char* ws = (char*)d_ws;
    u16* xb   = (u16*)(ws);                          // 16 MiB  [8192][1024] bf16 x
    u16* wqb  = (u16*)(ws + (size_t)(16 << 20));     //  2 MiB
    u16* wob  = (u16*)(ws + (size_t)(18 << 20));     //  2 MiB
    u16* qkvb = (u16*)(ws + (size_t)(20 << 20));     // 16 MiB  [64][2048][64]
    u16* attb = xb;                                  // reuse x-bf16 buffer for attention output

    const int n4x = (MM * D_MODEL) / 4;       // 2097152
    const int n4w = (D_MODEL * D_MODEL) / 4;  // 262144
    cvt_kernel<<<n4x / 256, 256, 0, stream>>>(x,  xb,  n4x);
    cvt_kernel<<<n4w / 256, 256, 0, stream>>>(wq, wqb, n4w);
    cvt_kernel<<<n4w / 256, 256, 0, stream>>>(wo, wob, n4w);

    gemm_qkv_kernel<<<(MM/128) * (D_MODEL/128), 256, 0, stream>>>(xb, wqb, qkvb);
    attn_kernel<<<BB * NH * (SS/128), 256, 0, stream>>>(qkvb, attb);
    gemm_out_kernel<<<(MM/128) * (D_MODEL/128), 256, 0, stream>>>(attb, wob, bo, (float*)d_out);
}

// Round 2
// 290.632 us; speedup vs baseline: 1.0468x; 1.0468x over previous
//
#include <hip/hip_runtime.h>
#include <stdint.h>

typedef unsigned short u16;
typedef __bf16 bf16x8 __attribute__((ext_vector_type(8)));
typedef float f32x4 __attribute__((ext_vector_type(4)));

#define D_MODEL 1024
#define NH 16
#define DHEAD 64
#define BB 4
#define SS 2048
#define MM (BB*SS)   // 8192 rows

__device__ __forceinline__ u16 f2bf(float f) {
    unsigned int u = __float_as_uint(f);
    u += 0x7fffu + ((u >> 16) & 1u);   // round-to-nearest-even
    return (u16)(u >> 16);
}
__device__ __forceinline__ float bf2f(u16 s) {
    return __uint_as_float(((unsigned int)s) << 16);
}

union U8 {
    uint4 q;
    u16   v[8];
    bf16x8 f;
};

// ---------------------------------------------------------------- cvt f32->bf16
__global__ __launch_bounds__(256) void cvt_kernel(const float* __restrict__ src,
                                                  u16* __restrict__ dst, int n4) {
    int i = blockIdx.x * 256 + threadIdx.x;
    if (i < n4) {
        float4 f = ((const float4*)src)[i];
        u16 o[4] = { f2bf(f.x), f2bf(f.y), f2bf(f.z), f2bf(f.w) };
        ((uint2*)dst)[i] = *(const uint2*)o;
    }
}

// ---------------------------------------------------------------- transpose qkv[bh][s][dh] -> qkvT[bh][dh][s]
// 64x64 tiles. LDS writes: all 32 banks 2-way (free); reads balanced.
__global__ __launch_bounds__(256) void transpose_kernel(const u16* __restrict__ src,
                                                        u16* __restrict__ dst) {
    __shared__ __align__(16) u16 Ls[64 * 72];   // [dh][s], stride 72
    const int t = threadIdx.x;
    const int bh = blockIdx.x >> 5;
    const int s0 = (blockIdx.x & 31) * 64;

    const int s  = t & 63;
    const int dg = t >> 6;          // 0..3 -> dh group of 16
    const u16* sp = src + ((size_t)(bh * SS) + s0 + s) * DHEAD + dg * 16;
#pragma unroll
    for (int c = 0; c < 2; ++c) {
        U8 raw; raw.q = *(const uint4*)(sp + c * 8);
#pragma unroll
        for (int j = 0; j < 8; ++j)
            Ls[(dg * 16 + c * 8 + j) * 72 + s] = raw.v[j];
    }
    __syncthreads();

    const int dh  = t >> 2;
    const int sc  = (t & 3) * 16;
    u16* op = dst + ((size_t)(bh * DHEAD) + dh) * SS + s0 + sc;
#pragma unroll
    for (int c = 0; c < 2; ++c)
        *(uint4*)(op + c * 8) = *(const uint4*)(Ls + dh * 72 + sc + c * 8);
}

// ---------------------------------------------------------------- GEMM1: qkv = x @ Wqkv^T, permuted bf16 out
__global__ __launch_bounds__(256) void gemm_qkv_kernel(const u16* __restrict__ A,   // [8192][1024]
                                                       const u16* __restrict__ Bt,  // [1024][1024] (N,K)
                                                       u16* __restrict__ Cq)        // [B][H][S][64]
{
    __shared__ __align__(16) u16 As[128*32];
    __shared__ __align__(16) u16 Bs[128*32];

    const int tid  = threadIdx.x;
    const int wave = tid >> 6;
    const int lane = tid & 63;
    const int quad = lane >> 4;
    const int l16  = lane & 15;
    const int bm = blockIdx.x >> 3;
    const int bn = blockIdx.x & 7;
    const int wm = wave >> 1, wn = wave & 1;

    f32x4 acc[4][4] = {};

    const int c0 = tid,        r0 = c0 >> 2, kc0 = (c0 & 3) * 8;
    const int c1 = tid + 256,  r1 = c1 >> 2, kc1 = (c1 & 3) * 8;

    const u16* Ab = A  + (size_t)(bm * 128) * D_MODEL;
    const u16* Bb = Bt + (size_t)(bn * 128) * D_MODEL;

    for (int k0 = 0; k0 < D_MODEL; k0 += 32) {
        __builtin_amdgcn_global_load_lds(
            (__attribute__((address_space(1))) void*)(Ab + (size_t)r0 * D_MODEL + k0 + kc0),
            (__attribute__((address_space(3))) void*)(As + c0 * 8), 16, 0, 0);
        __builtin_amdgcn_global_load_lds(
            (__attribute__((address_space(1))) void*)(Ab + (size_t)r1 * D_MODEL + k0 + kc1),
            (__attribute__((address_space(3))) void*)(As + c1 * 8), 16, 0, 0);
        __builtin_amdgcn_global_load_lds(
            (__attribute__((address_space(1))) void*)(Bb + (size_t)r0 * D_MODEL + k0 + kc0),
            (__attribute__((address_space(3))) void*)(Bs + c0 * 8), 16, 0, 0);
        __builtin_amdgcn_global_load_lds(
            (__attribute__((address_space(1))) void*)(Bb + (size_t)r1 * D_MODEL + k0 + kc1),
            (__attribute__((address_space(3))) void*)(Bs + c1 * 8), 16, 0, 0);
        __syncthreads();

        bf16x8 af[4], bfr[4];
#pragma unroll
        for (int t = 0; t < 4; ++t)
            af[t] = *(const bf16x8*)(const void*)(As + (wm*64 + t*16 + l16)*32 + quad*8);
#pragma unroll
        for (int t = 0; t < 4; ++t)
            bfr[t] = *(const bf16x8*)(const void*)(Bs + (wn*64 + t*16 + l16)*32 + quad*8);
#pragma unroll
        for (int i = 0; i < 4; ++i)
#pragma unroll
            for (int j = 0; j < 4; ++j)
                acc[i][j] = __builtin_amdgcn_mfma_f32_16x16x32_bf16(af[i], bfr[j], acc[i][j], 0, 0, 0);
        __syncthreads();
    }

    const int rowbase = bm*128 + wm*64;
    const int colbase = bn*128 + wn*64;
#pragma unroll
    for (int j = 0; j < 4; ++j) {
        const int col = colbase + j*16 + l16;
        const int h = col >> 6, dh = col & 63;
#pragma unroll
        for (int i = 0; i < 4; ++i) {
#pragma unroll
            for (int r = 0; r < 4; ++r) {
                const int row = rowbase + i*16 + quad*4 + r;
                const int b = row >> 11, s = row & (SS - 1);
                Cq[(((size_t)(b*NH + h))*SS + s)*DHEAD + dh] = f2bf(acc[i][j][r]);
            }
        }
    }
}

// ---------------------------------------------------------------- GEMM2: out = attn @ Wout^T + bias (fp32 out)
__global__ __launch_bounds__(256) void gemm_out_kernel(const u16* __restrict__ A,   // [8192][1024]
                                                       const u16* __restrict__ Bt,  // [1024][1024]
                                                       const float* __restrict__ Bo,
                                                       float* __restrict__ Out)     // [8192][1024]
{
    __shared__ __align__(16) u16 As[128*32];
    __shared__ __align__(16) u16 Bs[128*32];

    const int tid  = threadIdx.x;
    const int wave = tid >> 6;
    const int lane = tid & 63;
    const int quad = lane >> 4;
    const int l16  = lane & 15;
    const int bm = blockIdx.x >> 3;
    const int bn = blockIdx.x & 7;
    const int wm = wave >> 1, wn = wave & 1;

    f32x4 acc[4][4] = {};

    const int c0 = tid,        r0 = c0 >> 2, kc0 = (c0 & 3) * 8;
    const int c1 = tid + 256,  r1 = c1 >> 2, kc1 = (c1 & 3) * 8;

    const u16* Ab = A  + (size_t)(bm * 128) * D_MODEL;
    const u16* Bb = Bt + (size_t)(bn * 128) * D_MODEL;

    for (int k0 = 0; k0 < D_MODEL; k0 += 32) {
        __builtin_amdgcn_global_load_lds(
            (__attribute__((address_space(1))) void*)(Ab + (size_t)r0 * D_MODEL + k0 + kc0),
            (__attribute__((address_space(3))) void*)(As + c0 * 8), 16, 0, 0);
        __builtin_amdgcn_global_load_lds(
            (__attribute__((address_space(1))) void*)(Ab + (size_t)r1 * D_MODEL + k0 + kc1),
            (__attribute__((address_space(3))) void*)(As + c1 * 8), 16, 0, 0);
        __builtin_amdgcn_global_load_lds(
            (__attribute__((address_space(1))) void*)(Bb + (size_t)r0 * D_MODEL + k0 + kc0),
            (__attribute__((address_space(3))) void*)(Bs + c0 * 8), 16, 0, 0);
        __builtin_amdgcn_global_load_lds(
            (__attribute__((address_space(1))) void*)(Bb + (size_t)r1 * D_MODEL + k0 + kc1),
            (__attribute__((address_space(3))) void*)(Bs + c1 * 8), 16, 0, 0);
        __syncthreads();

        bf16x8 af[4], bfr[4];
#pragma unroll
        for (int t = 0; t < 4; ++t)
            af[t] = *(const bf16x8*)(const void*)(As + (wm*64 + t*16 + l16)*32 + quad*8);
#pragma unroll
        for (int t = 0; t < 4; ++t)
            bfr[t] = *(const bf16x8*)(const void*)(Bs + (wn*64 + t*16 + l16)*32 + quad*8);
#pragma unroll
        for (int i = 0; i < 4; ++i)
#pragma unroll
            for (int j = 0; j < 4; ++j)
                acc[i][j] = __builtin_amdgcn_mfma_f32_16x16x32_bf16(af[i], bfr[j], acc[i][j], 0, 0, 0);
        __syncthreads();
    }

    const int rowbase = bm*128 + wm*64;
    const int colbase = bn*128 + wn*64;
#pragma unroll
    for (int j = 0; j < 4; ++j) {
        const int col = colbase + j*16 + l16;
        const float bias = Bo[col];
#pragma unroll
        for (int i = 0; i < 4; ++i) {
#pragma unroll
            for (int r = 0; r < 4; ++r) {
                const int row = rowbase + i*16 + quad*4 + r;
                Out[(size_t)row * D_MODEL + col] = acc[i][j][r] + bias;
            }
        }
    }
}

// ---------------------------------------------------------------- attention (Q=K=V), no-max online softmax
// V staged via global_load_lds from pre-transposed qkvT; P stride 36 (conflict-free).
__global__ __launch_bounds__(256) void attn_kernel(const u16* __restrict__ qkv,   // [B*H][2048][64]
                                                   const u16* __restrict__ qkvT,  // [B*H][64][2048]
                                                   u16* __restrict__ outb)        // [B][S][1024]
{
    __shared__ __align__(16) u16 Ks[32*72];     // [key][dh], stride 72
    __shared__ __align__(16) u16 Vt[64*32];     // [dh][key], unpadded (global_load_lds dest)
    __shared__ __align__(16) u16 Ps[4*32*36];   // per-wave P, stride 36

    const int tid  = threadIdx.x;
    const int wave = tid >> 6;
    const int lane = tid & 63;
    const int quad = lane >> 4;
    const int l16  = lane & 15;

    const int bh   = blockIdx.x >> 4;   // b*16+h
    const int qblk = blockIdx.x & 15;
    const u16* base  = qkv  + (size_t)bh * SS * DHEAD;
    const u16* baseT = qkvT + (size_t)bh * DHEAD * SS
                     + (size_t)(wave * 16 + (lane >> 2)) * SS + (lane & 3) * 8;
    const int qbase = qblk * 128 + wave * 32;

    const float qscale = 0.125f * 1.4426950408889634f; // fold 1/sqrt(64) and log2(e)

    // preload scaled Q fragments (A-operand layout)
    bf16x8 aq[2][2];
#pragma unroll
    for (int mt = 0; mt < 2; ++mt)
#pragma unroll
        for (int ks = 0; ks < 2; ++ks) {
            U8 raw; raw.q = *(const uint4*)(base + (size_t)(qbase + mt*16 + l16)*DHEAD + ks*32 + quad*8);
            U8 w;
#pragma unroll
            for (int j = 0; j < 8; ++j) w.v[j] = f2bf(bf2f(raw.v[j]) * qscale);
            aq[mt][ks] = w.f;
        }

    bf16x8 ones;
#pragma unroll
    for (int j = 0; j < 8; ++j) ones[j] = (__bf16)1.0f;

    f32x4 o[2][4] = {};
    f32x4 lsum[2] = {};

    u16* Pw = Ps + wave * (32*36);
    const int skey = tid >> 3, sdh = (tid & 7) * 8;

    for (int kt = 0; kt < SS/32; ++kt) {
        // stage K tile (padded, via registers) and V tile (unpadded, via DMA)
        *(uint4*)(Ks + skey*72 + sdh) = *(const uint4*)(base + (size_t)(kt*32 + skey)*DHEAD + sdh);
        __builtin_amdgcn_global_load_lds(
            (__attribute__((address_space(1))) void*)(baseT + kt*32),
            (__attribute__((address_space(3))) void*)(Vt + wave * 512), 16, 0, 0);
        __syncthreads();

        // S = Q' K^T  (already in exp2 domain)
        f32x4 s[2][2] = {};
#pragma unroll
        for (int ks = 0; ks < 2; ++ks) {
            bf16x8 bk[2];
#pragma unroll
            for (int nt = 0; nt < 2; ++nt)
                bk[nt] = *(const bf16x8*)(const void*)(Ks + (nt*16 + l16)*72 + ks*32 + quad*8);
#pragma unroll
            for (int mt = 0; mt < 2; ++mt)
#pragma unroll
                for (int nt = 0; nt < 2; ++nt)
                    s[mt][nt] = __builtin_amdgcn_mfma_f32_16x16x32_bf16(aq[mt][ks], bk[nt], s[mt][nt], 0, 0, 0);
        }

        // P = exp2(S), stash in wave-private LDS (stride 36: conflict-free writes)
#pragma unroll
        for (int mt = 0; mt < 2; ++mt)
#pragma unroll
            for (int nt = 0; nt < 2; ++nt)
#pragma unroll
                for (int r = 0; r < 4; ++r) {
                    float p = __builtin_amdgcn_exp2f(s[mt][nt][r]);
                    Pw[(mt*16 + quad*4 + r)*36 + nt*16 + l16] = f2bf(p);
                }

        bf16x8 ap[2];
#pragma unroll
        for (int mt = 0; mt < 2; ++mt) {
            U8 a;
            *(uint2*)&a.v[0] = *(const uint2*)(const void*)(Pw + (mt*16 + l16)*36 + quad*8);
            *(uint2*)&a.v[4] = *(const uint2*)(const void*)(Pw + (mt*16 + l16)*36 + quad*8 + 4);
            ap[mt] = a.f;
        }

        bf16x8 bv[4];
#pragma unroll
        for (int nt = 0; nt < 4; ++nt)
            bv[nt] = *(const bf16x8*)(const void*)(Vt + (nt*16 + l16)*32 + quad*8);

#pragma unroll
        for (int mt = 0; mt < 2; ++mt) {
            lsum[mt] = __builtin_amdgcn_mfma_f32_16x16x32_bf16(ap[mt], ones, lsum[mt], 0, 0, 0);
#pragma unroll
            for (int nt = 0; nt < 4; ++nt)
                o[mt][nt] = __builtin_amdgcn_mfma_f32_16x16x32_bf16(ap[mt], bv[nt], o[mt][nt], 0, 0, 0);
        }
        __syncthreads();
    }

    const int b = bh >> 4, h = bh & 15;
#pragma unroll
    for (int mt = 0; mt < 2; ++mt) {
        float inv[4];
#pragma unroll
        for (int r = 0; r < 4; ++r) inv[r] = 1.0f / lsum[mt][r];
#pragma unroll
        for (int nt = 0; nt < 4; ++nt) {
            const int col = h*64 + nt*16 + l16;
#pragma unroll
            for (int r = 0; r < 4; ++r) {
                const int srow = qbase + mt*16 + quad*4 + r;
                outb[((size_t)(b*SS + srow))*D_MODEL + col] = f2bf(o[mt][nt][r] * inv[r]);
            }
        }
    }
}

// ---------------------------------------------------------------- launcher
extern "C" void kernel_launch(void* const* d_in, const int* in_sizes, int n_in,
                              void* d_out, int out_size, void* d_ws, size_t ws_size,
                              hipStream_t stream)
{
    (void)in_sizes; (void)n_in; (void)out_size; (void)ws_size;
    const float* x  = (const float*)d_in[0];
    const float* wq = (const float*)d_in[1];
    const float* wo = (const float*)d_in[2];
    const float* bo = (const float*)d_in[3];

    char* ws = (char*)d_ws;
    u16* xb    = (u16*)(ws);                          // 16 MiB  [8192][1024] bf16 x
    u16* wqb   = (u16*)(ws + (size_t)(16 << 20));     //  2 MiB
    u16* wob   = (u16*)(ws + (size_t)(18 << 20));     //  2 MiB
    u16* qkvb  = (u16*)(ws + (size_t)(20 << 20));     // 16 MiB  [64][2048][64]
    u16* qkvTb = (u16*)(ws + (size_t)(36 << 20));     // 16 MiB  [64][64][2048]
    u16* attb  = xb;                                  // reuse x-bf16 buffer for attention output

    const int n4x = (MM * D_MODEL) / 4;       // 2097152
    const int n4w = (D_MODEL * D_MODEL) / 4;  // 262144
    cvt_kernel<<<n4x / 256, 256, 0, stream>>>(x,  xb,  n4x);
    cvt_kernel<<<n4w / 256, 256, 0, stream>>>(wq, wqb, n4w);
    cvt_kernel<<<n4w / 256, 256, 0, stream>>>(wo, wob, n4w);

    gemm_qkv_kernel<<<(MM/128) * (D_MODEL/128), 256, 0, stream>>>(xb, wqb, qkvb);
    transpose_kernel<<<BB * NH * (SS/64), 256, 0, stream>>>(qkvb, qkvTb);
    attn_kernel<<<BB * NH * (SS/128), 256, 0, stream>>>(qkvb, qkvTb, attb);
    gemm_out_kernel<<<(MM/128) * (D_MODEL/128), 256, 0, stream>>>(attb, wob, bo, (float*)d_out);
}

// Round 3
// 286.403 us; speedup vs baseline: 1.0623x; 1.0148x over previous
//
#include <hip/hip_runtime.h>
#include <stdint.h>

typedef unsigned short u16;
typedef __bf16 bf16x8 __attribute__((ext_vector_type(8)));
typedef float f32x4 __attribute__((ext_vector_type(4)));

#define D_MODEL 1024
#define NH 16
#define DHEAD 64
#define BB 4
#define SS 2048
#define MM (BB*SS)   // 8192 rows

__device__ __forceinline__ u16 f2bf(float f) {
    unsigned int u = __float_as_uint(f);
    u += 0x7fffu + ((u >> 16) & 1u);   // round-to-nearest-even
    return (u16)(u >> 16);
}
__device__ __forceinline__ u16 f2bf_rhu(float f) {  // round-half-up (2 VALU ops)
    return (u16)((__float_as_uint(f) + 0x8000u) >> 16);
}
__device__ __forceinline__ float bf2f(u16 s) {
    return __uint_as_float(((unsigned int)s) << 16);
}

union U8 {
    uint4 q;
    u16   v[8];
    bf16x8 f;
};

// ---------------------------------------------------------------- cvt f32->bf16
__global__ __launch_bounds__(256) void cvt_kernel(const float* __restrict__ src,
                                                  u16* __restrict__ dst, int n4) {
    int i = blockIdx.x * 256 + threadIdx.x;
    if (i < n4) {
        float4 f = ((const float4*)src)[i];
        u16 o[4] = { f2bf(f.x), f2bf(f.y), f2bf(f.z), f2bf(f.w) };
        ((uint2*)dst)[i] = *(const uint2*)o;
    }
}

// ---------------------------------------------------------------- transpose qkv[bh][s][dh] -> qkvT[bh][dh][s]
__global__ __launch_bounds__(256) void transpose_kernel(const u16* __restrict__ src,
                                                        u16* __restrict__ dst) {
    __shared__ __align__(16) u16 Ls[64 * 72];   // [dh][s], stride 72
    const int t = threadIdx.x;
    const int bh = blockIdx.x >> 5;
    const int s0 = (blockIdx.x & 31) * 64;

    const int s  = t & 63;
    const int dg = t >> 6;          // 0..3 -> dh group of 16
    const u16* sp = src + ((size_t)(bh * SS) + s0 + s) * DHEAD + dg * 16;
#pragma unroll
    for (int c = 0; c < 2; ++c) {
        U8 raw; raw.q = *(const uint4*)(sp + c * 8);
#pragma unroll
        for (int j = 0; j < 8; ++j)
            Ls[(dg * 16 + c * 8 + j) * 72 + s] = raw.v[j];
    }
    __syncthreads();

    const int dh  = t >> 2;
    const int sc  = (t & 3) * 16;
    u16* op = dst + ((size_t)(bh * DHEAD) + dh) * SS + s0 + sc;
#pragma unroll
    for (int c = 0; c < 2; ++c)
        *(uint4*)(op + c * 8) = *(const uint4*)(Ls + dh * 72 + sc + c * 8);
}

// ================================================================ GEMM core (BK=64, XOR-swizzled LDS)
// As_phys[row][chunk] = A_log[row][chunk ^ (row&7)]; frag reads un-swizzle.
// Staging is lane-contiguous (global_load_lds dest = wavebase + lane*16B).
template <bool PERMUTE_OUT>
__device__ __forceinline__ void gemm_body(const u16* __restrict__ A,
                                          const u16* __restrict__ Bt,
                                          const float* __restrict__ Bo,
                                          u16* __restrict__ Cq, float* __restrict__ Out)
{
    __shared__ __align__(16) u16 As[128*64];   // 16 KB
    __shared__ __align__(16) u16 Bs[128*64];   // 16 KB

    const int tid  = threadIdx.x;
    const int wave = tid >> 6;
    const int lane = tid & 63;
    const int quad = lane >> 4;
    const int l16  = lane & 15;
    const int bm = blockIdx.x >> 3;
    const int bn = blockIdx.x & 7;
    const int wm = wave >> 1, wn = wave & 1;

    f32x4 acc[4][4] = {};

    const int rp = tid >> 3;              // row in 32-row pass
    const int ch = tid & 7;               // physical chunk (8 elems)
    const int sc = ch ^ (rp & 7);         // source (logical) chunk

    const u16* Ab = A  + (size_t)(bm * 128 + rp) * D_MODEL + sc * 8;
    const u16* Bb = Bt + (size_t)(bn * 128 + rp) * D_MODEL + sc * 8;
    const int xr = l16 & 7;               // frag-read un-swizzle key

    for (int k0 = 0; k0 < D_MODEL; k0 += 64) {
#pragma unroll
        for (int p = 0; p < 4; ++p) {
            __builtin_amdgcn_global_load_lds(
                (__attribute__((address_space(1))) void*)(Ab + (size_t)(32*p) * D_MODEL + k0),
                (__attribute__((address_space(3))) void*)(As + p*2048 + tid*8), 16, 0, 0);
            __builtin_amdgcn_global_load_lds(
                (__attribute__((address_space(1))) void*)(Bb + (size_t)(32*p) * D_MODEL + k0),
                (__attribute__((address_space(3))) void*)(Bs + p*2048 + tid*8), 16, 0, 0);
        }
        __syncthreads();

#pragma unroll
        for (int ks = 0; ks < 2; ++ks) {
            bf16x8 af[4], bfr[4];
#pragma unroll
            for (int t = 0; t < 4; ++t)
                af[t] = *(const bf16x8*)(const void*)(
                    As + (wm*64 + t*16 + l16)*64 + (((ks*4 + quad) ^ xr) * 8));
#pragma unroll
            for (int t = 0; t < 4; ++t)
                bfr[t] = *(const bf16x8*)(const void*)(
                    Bs + (wn*64 + t*16 + l16)*64 + (((ks*4 + quad) ^ xr) * 8));
#pragma unroll
            for (int i = 0; i < 4; ++i)
#pragma unroll
                for (int j = 0; j < 4; ++j)
                    acc[i][j] = __builtin_amdgcn_mfma_f32_16x16x32_bf16(af[i], bfr[j], acc[i][j], 0, 0, 0);
        }
        __syncthreads();
    }

    const int rowbase = bm*128 + wm*64;
    const int colbase = bn*128 + wn*64;
    if (PERMUTE_OUT) {
#pragma unroll
        for (int j = 0; j < 4; ++j) {
            const int col = colbase + j*16 + l16;
            const int h = col >> 6, dh = col & 63;
#pragma unroll
            for (int i = 0; i < 4; ++i) {
#pragma unroll
                for (int r = 0; r < 4; ++r) {
                    const int row = rowbase + i*16 + quad*4 + r;
                    const int b = row >> 11, s = row & (SS - 1);
                    Cq[(((size_t)(b*NH + h))*SS + s)*DHEAD + dh] = f2bf(acc[i][j][r]);
                }
            }
        }
    } else {
#pragma unroll
        for (int j = 0; j < 4; ++j) {
            const int col = colbase + j*16 + l16;
            const float bias = Bo[col];
#pragma unroll
            for (int i = 0; i < 4; ++i) {
#pragma unroll
                for (int r = 0; r < 4; ++r) {
                    const int row = rowbase + i*16 + quad*4 + r;
                    Out[(size_t)row * D_MODEL + col] = acc[i][j][r] + bias;
                }
            }
        }
    }
}

__global__ __launch_bounds__(256) void gemm_qkv_kernel(const u16* __restrict__ A,
                                                       const u16* __restrict__ Bt,
                                                       u16* __restrict__ Cq) {
    gemm_body<true>(A, Bt, nullptr, Cq, nullptr);
}

__global__ __launch_bounds__(256) void gemm_out_kernel(const u16* __restrict__ A,
                                                       const u16* __restrict__ Bt,
                                                       const float* __restrict__ Bo,
                                                       float* __restrict__ Out) {
    gemm_body<false>(A, Bt, Bo, nullptr, Out);
}

// ---------------------------------------------------------------- attention (Q=K=V), 16 q-rows/wave
__global__ __launch_bounds__(256) void attn_kernel(const u16* __restrict__ qkv,   // [B*H][2048][64]
                                                   const u16* __restrict__ qkvT,  // [B*H][64][2048]
                                                   u16* __restrict__ outb)        // [B][S][1024]
{
    __shared__ __align__(16) u16 Ks[32*72];     // [key][dh], stride 72
    __shared__ __align__(16) u16 Vt[64*32];     // [dh][key], unpadded (DMA dest)
    __shared__ __align__(16) u16 Ps[4*16*36];   // per-wave P (16 q-rows), stride 36

    const int tid  = threadIdx.x;
    const int wave = tid >> 6;
    const int lane = tid & 63;
    const int quad = lane >> 4;
    const int l16  = lane & 15;

    const int bh   = blockIdx.x >> 5;   // 64 of them
    const int qblk = blockIdx.x & 31;   // 32 q-blocks of 64 rows
    const u16* base  = qkv  + (size_t)bh * SS * DHEAD;
    const u16* baseT = qkvT + (size_t)bh * DHEAD * SS
                     + (size_t)(wave * 16 + (lane >> 2)) * SS + (lane & 3) * 8;
    const int qbase = qblk * 64 + wave * 16;

    const float qscale = 0.125f * 1.4426950408889634f; // 1/sqrt(64) * log2(e)

    // preload scaled Q fragments (A-operand layout), 16 rows
    bf16x8 aq[2];
#pragma unroll
    for (int ks = 0; ks < 2; ++ks) {
        U8 raw; raw.q = *(const uint4*)(base + (size_t)(qbase + l16)*DHEAD + ks*32 + quad*8);
        U8 w;
#pragma unroll
        for (int j = 0; j < 8; ++j) w.v[j] = f2bf(bf2f(raw.v[j]) * qscale);
        aq[ks] = w.f;
    }

    bf16x8 ones;
#pragma unroll
    for (int j = 0; j < 8; ++j) ones[j] = (__bf16)1.0f;

    f32x4 o[4] = {};
    f32x4 lsum = {};

    u16* Pw = Ps + wave * (16*36);
    const int skey = tid >> 3, sdh = (tid & 7) * 8;

    for (int kt = 0; kt < SS/32; ++kt) {
        // stage K tile (padded, via registers) and V tile (unpadded, via DMA)
        *(uint4*)(Ks + skey*72 + sdh) = *(const uint4*)(base + (size_t)(kt*32 + skey)*DHEAD + sdh);
        __builtin_amdgcn_global_load_lds(
            (__attribute__((address_space(1))) void*)(baseT + kt*32),
            (__attribute__((address_space(3))) void*)(Vt + wave * 512), 16, 0, 0);
        __syncthreads();

        // S = Q' K^T  (already in exp2 domain)
        f32x4 s[2] = {};
#pragma unroll
        for (int ks = 0; ks < 2; ++ks) {
            bf16x8 bk[2];
#pragma unroll
            for (int nt = 0; nt < 2; ++nt)
                bk[nt] = *(const bf16x8*)(const void*)(Ks + (nt*16 + l16)*72 + ks*32 + quad*8);
#pragma unroll
            for (int nt = 0; nt < 2; ++nt)
                s[nt] = __builtin_amdgcn_mfma_f32_16x16x32_bf16(aq[ks], bk[nt], s[nt], 0, 0, 0);
        }

        // P = exp2(S) -> wave-private LDS (stride 36, conflict-free)
#pragma unroll
        for (int nt = 0; nt < 2; ++nt)
#pragma unroll
            for (int r = 0; r < 4; ++r) {
                float p = __builtin_amdgcn_exp2f(s[nt][r]);
                Pw[(quad*4 + r)*36 + nt*16 + l16] = f2bf_rhu(p);
            }

        bf16x8 ap;
        {
            U8 a;
            *(uint2*)&a.v[0] = *(const uint2*)(const void*)(Pw + l16*36 + quad*8);
            *(uint2*)&a.v[4] = *(const uint2*)(const void*)(Pw + l16*36 + quad*8 + 4);
            ap = a.f;
        }

        bf16x8 bv[4];
#pragma unroll
        for (int nt = 0; nt < 4; ++nt)
            bv[nt] = *(const bf16x8*)(const void*)(Vt + (nt*16 + l16)*32 + quad*8);

        lsum = __builtin_amdgcn_mfma_f32_16x16x32_bf16(ap, ones, lsum, 0, 0, 0);
#pragma unroll
        for (int nt = 0; nt < 4; ++nt)
            o[nt] = __builtin_amdgcn_mfma_f32_16x16x32_bf16(ap, bv[nt], o[nt], 0, 0, 0);
        __syncthreads();
    }

    const int b = bh >> 4, h = bh & 15;
    float inv[4];
#pragma unroll
    for (int r = 0; r < 4; ++r) inv[r] = 1.0f / lsum[r];
#pragma unroll
    for (int nt = 0; nt < 4; ++nt) {
        const int col = h*64 + nt*16 + l16;
#pragma unroll
        for (int r = 0; r < 4; ++r) {
            const int srow = qbase + quad*4 + r;
            outb[((size_t)(b*SS + srow))*D_MODEL + col] = f2bf(o[nt][r] * inv[r]);
        }
    }
}

// ---------------------------------------------------------------- launcher
extern "C" void kernel_launch(void* const* d_in, const int* in_sizes, int n_in,
                              void* d_out, int out_size, void* d_ws, size_t ws_size,
                              hipStream_t stream)
{
    (void)in_sizes; (void)n_in; (void)out_size; (void)ws_size;
    const float* x  = (const float*)d_in[0];
    const float* wq = (const float*)d_in[1];
    const float* wo = (const float*)d_in[2];
    const float* bo = (const float*)d_in[3];

    char* ws = (char*)d_ws;
    u16* xb    = (u16*)(ws);                          // 16 MiB  [8192][1024] bf16 x
    u16* wqb   = (u16*)(ws + (size_t)(16 << 20));     //  2 MiB
    u16* wob   = (u16*)(ws + (size_t)(18 << 20));     //  2 MiB
    u16* qkvb  = (u16*)(ws + (size_t)(20 << 20));     // 16 MiB  [64][2048][64]
    u16* qkvTb = (u16*)(ws + (size_t)(36 << 20));     // 16 MiB  [64][64][2048]
    u16* attb  = xb;                                  // reuse x-bf16 buffer for attention output

    const int n4x = (MM * D_MODEL) / 4;       // 2097152
    const int n4w = (D_MODEL * D_MODEL) / 4;  // 262144
    cvt_kernel<<<n4x / 256, 256, 0, stream>>>(x,  xb,  n4x);
    cvt_kernel<<<n4w / 256, 256, 0, stream>>>(wq, wqb, n4w);
    cvt_kernel<<<n4w / 256, 256, 0, stream>>>(wo, wob, n4w);

    gemm_qkv_kernel<<<(MM/128) * (D_MODEL/128), 256, 0, stream>>>(xb, wqb, qkvb);
    transpose_kernel<<<BB * NH * (SS/64), 256, 0, stream>>>(qkvb, qkvTb);
    attn_kernel<<<BB * NH * (SS/64), 256, 0, stream>>>(qkvb, qkvTb, attb);
    gemm_out_kernel<<<(MM/128) * (D_MODEL/128), 256, 0, stream>>>(attb, wob, bo, (float*)d_out);
}

// Round 4
// 243.281 us; speedup vs baseline: 1.2506x; 1.1773x over previous
//
#include <hip/hip_runtime.h>
#include <hip/hip_bf16.h>
#include <stdint.h>

typedef unsigned short u16;
typedef unsigned int   u32;
typedef unsigned long long u64;
typedef __bf16 bf16x8 __attribute__((ext_vector_type(8)));
typedef float  f32x4  __attribute__((ext_vector_type(4)));

#define D_MODEL 1024
#define NH 16
#define DHEAD 64
#define BB 4
#define SS 2048
#define MM (BB*SS)   // 8192 rows

__device__ __forceinline__ u16 f2bf(float f) {
    unsigned int u = __float_as_uint(f);
    u += 0x7fffu + ((u >> 16) & 1u);   // RNE
    return (u16)(u >> 16);
}
__device__ __forceinline__ float bf2f(u16 s) {
    return __uint_as_float(((unsigned int)s) << 16);
}
__device__ __forceinline__ u32 pkbf(float a, float b) {  // v_cvt_pk_bf16_f32 (RNE)
    __hip_bfloat162 h = __float22bfloat162_rn(make_float2(a, b));
    return *(u32*)&h;
}

union U8 {
    uint4 q;
    u16   v[8];
    bf16x8 f;
};

// ---------------------------------------------------------------- merged cvt f32->bf16 (x, w_qkv, w_out)
#define N4X (MM * D_MODEL / 4)        // 2097152
#define N4W (D_MODEL * D_MODEL / 4)   // 262144
__global__ __launch_bounds__(256) void cvt_all_kernel(const float* __restrict__ x,
                                                      const float* __restrict__ wq,
                                                      const float* __restrict__ wo,
                                                      u16* __restrict__ xb,
                                                      u16* __restrict__ wqb,
                                                      u16* __restrict__ wob) {
    int i = blockIdx.x * 256 + threadIdx.x;
    const float* s; u16* d; int off;
    if (i < N4X)            { s = x;  d = xb;  off = i; }
    else if (i < N4X + N4W) { s = wq; d = wqb; off = i - N4X; }
    else                    { s = wo; d = wob; off = i - N4X - N4W; }
    float4 f = ((const float4*)s)[off];
    u32 o[2] = { pkbf(f.x, f.y), pkbf(f.z, f.w) };
    ((uint2*)d)[off] = *(const uint2*)o;
}

// ================================================================ GEMM core (BK=64, XOR-swizzled LDS)
template <bool PERMUTE_OUT>
__device__ __forceinline__ void gemm_body(const u16* __restrict__ A,
                                          const u16* __restrict__ Bt,
                                          const float* __restrict__ Bo,
                                          u16* __restrict__ Cq, u16* __restrict__ CqT,
                                          float* __restrict__ Out)
{
    __shared__ __align__(16) u16 As[128*64];
    __shared__ __align__(16) u16 Bs[128*64];

    const int tid  = threadIdx.x;
    const int wave = tid >> 6;
    const int lane = tid & 63;
    const int quad = lane >> 4;
    const int l16  = lane & 15;
    const int bm = blockIdx.x >> 3;
    const int bn = blockIdx.x & 7;
    const int wm = wave >> 1, wn = wave & 1;

    f32x4 acc[4][4] = {};

    const int rp = tid >> 3;              // row in 32-row pass
    const int ch = tid & 7;               // physical chunk (8 elems)
    const int sc = ch ^ (rp & 7);         // source (logical) chunk

    const u16* Ab = A  + (size_t)(bm * 128 + rp) * D_MODEL + sc * 8;
    const u16* Bb = Bt + (size_t)(bn * 128 + rp) * D_MODEL + sc * 8;
    const int xr = l16 & 7;

    for (int k0 = 0; k0 < D_MODEL; k0 += 64) {
#pragma unroll
        for (int p = 0; p < 4; ++p) {
            __builtin_amdgcn_global_load_lds(
                (__attribute__((address_space(1))) void*)(Ab + (size_t)(32*p) * D_MODEL + k0),
                (__attribute__((address_space(3))) void*)(As + p*2048 + tid*8), 16, 0, 0);
            __builtin_amdgcn_global_load_lds(
                (__attribute__((address_space(1))) void*)(Bb + (size_t)(32*p) * D_MODEL + k0),
                (__attribute__((address_space(3))) void*)(Bs + p*2048 + tid*8), 16, 0, 0);
        }
        __syncthreads();

#pragma unroll
        for (int ks = 0; ks < 2; ++ks) {
            bf16x8 af[4], bfr[4];
#pragma unroll
            for (int t = 0; t < 4; ++t)
                af[t] = *(const bf16x8*)(const void*)(
                    As + (wm*64 + t*16 + l16)*64 + (((ks*4 + quad) ^ xr) * 8));
#pragma unroll
            for (int t = 0; t < 4; ++t)
                bfr[t] = *(const bf16x8*)(const void*)(
                    Bs + (wn*64 + t*16 + l16)*64 + (((ks*4 + quad) ^ xr) * 8));
#pragma unroll
            for (int i = 0; i < 4; ++i)
#pragma unroll
                for (int j = 0; j < 4; ++j)
                    acc[i][j] = __builtin_amdgcn_mfma_f32_16x16x32_bf16(af[i], bfr[j], acc[i][j], 0, 0, 0);
        }
        __syncthreads();
    }

    const int rowbase = bm*128 + wm*64;
    const int colbase = bn*128 + wn*64;
    if (PERMUTE_OUT) {
#pragma unroll
        for (int j = 0; j < 4; ++j) {
            const int col = colbase + j*16 + l16;
            const int h = col >> 6, dh = col & 63;
#pragma unroll
            for (int i = 0; i < 4; ++i) {
                const int row0 = rowbase + i*16 + quad*4;
                const int b = row0 >> 11, s0 = row0 & (SS - 1);
                // qkv[b*NH+h][s][dh] : 4 scalar b16 stores (s stride 64)
#pragma unroll
                for (int r = 0; r < 4; ++r)
                    Cq[(((size_t)(b*NH + h))*SS + s0 + r)*DHEAD + dh] = f2bf(acc[i][j][r]);
                // qkvT[b*NH+h][dh][s] : 4 consecutive s -> packed 8B store
                u64 w = (u64)pkbf(acc[i][j][0], acc[i][j][1])
                      | ((u64)pkbf(acc[i][j][2], acc[i][j][3]) << 32);
                *(u64*)(CqT + ((size_t)((b*NH + h)*DHEAD + dh))*SS + s0) = w;
            }
        }
    } else {
#pragma unroll
        for (int j = 0; j < 4; ++j) {
            const int col = colbase + j*16 + l16;
            const float bias = Bo[col];
#pragma unroll
            for (int i = 0; i < 4; ++i) {
#pragma unroll
                for (int r = 0; r < 4; ++r) {
                    const int row = rowbase + i*16 + quad*4 + r;
                    Out[(size_t)row * D_MODEL + col] = acc[i][j][r] + bias;
                }
            }
        }
    }
}

__global__ __launch_bounds__(256) void gemm_qkv_kernel(const u16* __restrict__ A,
                                                       const u16* __restrict__ Bt,
                                                       u16* __restrict__ Cq,
                                                       u16* __restrict__ CqT) {
    gemm_body<true>(A, Bt, nullptr, Cq, CqT, nullptr);
}

__global__ __launch_bounds__(256) void gemm_out_kernel(const u16* __restrict__ A,
                                                       const u16* __restrict__ Bt,
                                                       const float* __restrict__ Bo,
                                                       float* __restrict__ Out) {
    gemm_body<false>(A, Bt, Bo, nullptr, nullptr, Out);
}

// ---------------------------------------------------------------- attention (Q=K=V), S^T formulation
// Wave owns 64 q-columns. S^T = K*Q^T -> D holds 4 consecutive keys/lane -> b64 P writes,
// b128 P reads as PV B-frags. O^T = V^T * P^T. K/V double-buffered via swizzled DMA.
__global__ __launch_bounds__(256) void attn_kernel(const u16* __restrict__ qkv,   // [B*H][2048][64]
                                                   const u16* __restrict__ qkvT,  // [B*H][64][2048]
                                                   u16* __restrict__ outb)        // [B][S][1024]
{
    __shared__ __align__(16) u16 Ks[2*2048];    // [buf][32 key][64 dh] chunk-swizzled
    __shared__ __align__(16) u16 Vt[2*2048];    // [buf][64 dh][32 key] chunk-swizzled
    __shared__ __align__(16) u16 Pl[4*2560];    // per-wave [64 q][keys], stride 40

    const int tid  = threadIdx.x;
    const int wave = tid >> 6;
    const int lane = tid & 63;
    const int quad = lane >> 4;
    const int l16  = lane & 15;

    const int bh   = blockIdx.x >> 3;
    const int qblk = blockIdx.x & 7;
    const int b = bh >> 4, h = bh & 15;
    const int qbase = qblk * 256 + wave * 64;

    const u16* Qp = qkv + (size_t)bh * SS * DHEAD;
    const float qscale = 0.125f * 1.4426950408889634f;  // 1/sqrt(64) * log2(e)

    // Q as B-operand frags: B[k=dh][n=q], lane reads 8 consecutive dh at fixed q
    bf16x8 qb[4][2];
#pragma unroll
    for (int nt = 0; nt < 4; ++nt)
#pragma unroll
        for (int ks = 0; ks < 2; ++ks) {
            U8 raw; raw.q = *(const uint4*)(Qp + (size_t)(qbase + nt*16 + l16)*DHEAD + ks*32 + quad*8);
            U8 w;
#pragma unroll
            for (int jj = 0; jj < 4; ++jj)
                ((u32*)&w)[jj] = pkbf(bf2f(raw.v[2*jj]) * qscale, bf2f(raw.v[2*jj+1]) * qscale);
            qb[nt][ks] = w.f;
        }

    // DMA staging sources (chunk-swizzled so frag reads are conflict-free)
    const int rK = tid >> 3, cK = (tid & 7) ^ ((rK >> 1) & 7);
    const u16* srcK = qkv  + (size_t)bh * SS * DHEAD + rK * DHEAD + cK * 8;
    const int rV = tid >> 2, cV = (tid & 3) ^ ((rV >> 1) & 3);
    const u16* srcV = qkvT + (size_t)bh * DHEAD * SS + (size_t)rV * SS + cV * 8;

    // frag read offsets
    const int h8 = (l16 >> 1) & 7, h4 = (l16 >> 1) & 3;
    const int ko0 = l16*64 + ((quad)     ^ h8) * 8;   // ks=0
    const int ko1 = l16*64 + ((4 + quad) ^ h8) * 8;   // ks=1
    const int vo  = l16*32 + ((quad) ^ h4) * 8;

    u16* Pw       = Pl + wave*2560 + l16*40 + quad*4;
    const u16* Pr = Pl + wave*2560 + l16*40 + quad*8;

    bf16x8 ones;
#pragma unroll
    for (int j = 0; j < 8; ++j) ones[j] = (__bf16)1.0f;

    f32x4 ot[4][4] = {};    // O^T[dh-tile][q-tile]
    f32x4 lsum[4]  = {};

    // prime buffer 0
    __builtin_amdgcn_global_load_lds(
        (__attribute__((address_space(1))) void*)(srcK),
        (__attribute__((address_space(3))) void*)(Ks + tid*8), 16, 0, 0);
    __builtin_amdgcn_global_load_lds(
        (__attribute__((address_space(1))) void*)(srcV),
        (__attribute__((address_space(3))) void*)(Vt + tid*8), 16, 0, 0);

#pragma unroll 2
    for (int kt = 0; kt < SS/32; ++kt) {
        __syncthreads();   // drains DMA for tile kt
        if (kt < SS/32 - 1) {   // prefetch kt+1 into other buffer (in flight during compute)
            __builtin_amdgcn_global_load_lds(
                (__attribute__((address_space(1))) void*)(srcK + (size_t)(kt+1)*32*DHEAD),
                (__attribute__((address_space(3))) void*)(Ks + ((kt+1)&1)*2048 + tid*8), 16, 0, 0);
            __builtin_amdgcn_global_load_lds(
                (__attribute__((address_space(1))) void*)(srcV + (kt+1)*32),
                (__attribute__((address_space(3))) void*)(Vt + ((kt+1)&1)*2048 + tid*8), 16, 0, 0);
        }
        const u16* Kb = Ks + (kt&1)*2048;
        const u16* Vb = Vt + (kt&1)*2048;

        // S^T = K * Q^T, then P^T = exp2(S^T) -> LDS (b64 packed writes)
#pragma unroll
        for (int mt = 0; mt < 2; ++mt) {
            f32x4 s[4] = {};
            bf16x8 kf0 = *(const bf16x8*)(const void*)(Kb + mt*1024 + ko0);
            bf16x8 kf1 = *(const bf16x8*)(const void*)(Kb + mt*1024 + ko1);
#pragma unroll
            for (int nt = 0; nt < 4; ++nt)
                s[nt] = __builtin_amdgcn_mfma_f32_16x16x32_bf16(kf0, qb[nt][0], s[nt], 0, 0, 0);
#pragma unroll
            for (int nt = 0; nt < 4; ++nt)
                s[nt] = __builtin_amdgcn_mfma_f32_16x16x32_bf16(kf1, qb[nt][1], s[nt], 0, 0, 0);
#pragma unroll
            for (int nt = 0; nt < 4; ++nt) {
                float p0 = __builtin_amdgcn_exp2f(s[nt][0]);
                float p1 = __builtin_amdgcn_exp2f(s[nt][1]);
                float p2 = __builtin_amdgcn_exp2f(s[nt][2]);
                float p3 = __builtin_amdgcn_exp2f(s[nt][3]);
                u64 w = (u64)pkbf(p0, p1) | ((u64)pkbf(p2, p3) << 32);
                *(u64*)(Pw + nt*640 + mt*16) = w;
            }
        }

        // P^T frags (B-operand: 8 consecutive keys at fixed q) + V^T frags (A-operand)
        bf16x8 pf[4];
#pragma unroll
        for (int nt = 0; nt < 4; ++nt)
            pf[nt] = *(const bf16x8*)(const void*)(Pr + nt*640);
#pragma unroll
        for (int nt = 0; nt < 4; ++nt)
            lsum[nt] = __builtin_amdgcn_mfma_f32_16x16x32_bf16(ones, pf[nt], lsum[nt], 0, 0, 0);
        bf16x8 vf[4];
#pragma unroll
        for (int dt = 0; dt < 4; ++dt)
            vf[dt] = *(const bf16x8*)(const void*)(Vb + dt*512 + vo);
#pragma unroll
        for (int dt = 0; dt < 4; ++dt)
#pragma unroll
            for (int nt = 0; nt < 4; ++nt)
                ot[dt][nt] = __builtin_amdgcn_mfma_f32_16x16x32_bf16(vf[dt], pf[nt], ot[dt][nt], 0, 0, 0);
    }

    // epilogue: O = O^T / lsum, packed 8B stores (4 consecutive dh per lane)
    float inv[4];
#pragma unroll
    for (int nt = 0; nt < 4; ++nt) inv[nt] = 1.0f / lsum[nt][0];
#pragma unroll
    for (int dt = 0; dt < 4; ++dt)
#pragma unroll
        for (int nt = 0; nt < 4; ++nt) {
            u64 w = (u64)pkbf(ot[dt][nt][0]*inv[nt], ot[dt][nt][1]*inv[nt])
                  | ((u64)pkbf(ot[dt][nt][2]*inv[nt], ot[dt][nt][3]*inv[nt]) << 32);
            *(u64*)(outb + ((size_t)(b*SS + qbase + nt*16 + l16))*D_MODEL
                         + h*64 + dt*16 + quad*4) = w;
        }
}

// ---------------------------------------------------------------- launcher
extern "C" void kernel_launch(void* const* d_in, const int* in_sizes, int n_in,
                              void* d_out, int out_size, void* d_ws, size_t ws_size,
                              hipStream_t stream)
{
    (void)in_sizes; (void)n_in; (void)out_size; (void)ws_size;
    const float* x  = (const float*)d_in[0];
    const float* wq = (const float*)d_in[1];
    const float* wo = (const float*)d_in[2];
    const float* bo = (const float*)d_in[3];

    char* ws = (char*)d_ws;
    u16* xb    = (u16*)(ws);                          // 16 MiB  [8192][1024] bf16 x
    u16* wqb   = (u16*)(ws + (size_t)(16 << 20));     //  2 MiB
    u16* wob   = (u16*)(ws + (size_t)(18 << 20));     //  2 MiB
    u16* qkvb  = (u16*)(ws + (size_t)(20 << 20));     // 16 MiB  [64][2048][64]
    u16* qkvTb = (u16*)(ws + (size_t)(36 << 20));     // 16 MiB  [64][64][2048]
    u16* attb  = xb;                                  // reuse x-bf16 buffer for attention output

    cvt_all_kernel<<<(N4X + 2*N4W) / 256, 256, 0, stream>>>(x, wq, wo, xb, wqb, wob);
    gemm_qkv_kernel<<<(MM/128) * (D_MODEL/128), 256, 0, stream>>>(xb, wqb, qkvb, qkvTb);
    attn_kernel<<<BB * NH * (SS/256), 256, 0, stream>>>(qkvb, qkvTb, attb);
    gemm_out_kernel<<<(MM/128) * (D_MODEL/128), 256, 0, stream>>>(attb, wob, bo, (float*)d_out);
}

// Round 5
// 236.789 us; speedup vs baseline: 1.2849x; 1.0274x over previous
//
#include <hip/hip_runtime.h>
#include <hip/hip_bf16.h>
#include <stdint.h>

typedef unsigned short u16;
typedef unsigned int   u32;
typedef unsigned long long u64;
typedef __bf16 bf16x8 __attribute__((ext_vector_type(8)));
typedef float  f32x4  __attribute__((ext_vector_type(4)));

#define D_MODEL 1024
#define NH 16
#define DHEAD 64
#define BB 4
#define SS 2048
#define MM (BB*SS)   // 8192 rows

__device__ __forceinline__ u16 f2bf(float f) {
    unsigned int u = __float_as_uint(f);
    u += 0x7fffu + ((u >> 16) & 1u);   // RNE
    return (u16)(u >> 16);
}
__device__ __forceinline__ float bf2f(u16 s) {
    return __uint_as_float(((unsigned int)s) << 16);
}
__device__ __forceinline__ u32 pkbf(float a, float b) {  // v_cvt_pk_bf16_f32 (RNE)
    __hip_bfloat162 h = __float22bfloat162_rn(make_float2(a, b));
    return *(u32*)&h;
}

union U8 {
    uint4 q;
    u16   v[8];
    bf16x8 f;
};

// ---------------------------------------------------------------- merged cvt f32->bf16 (x, w_qkv, w_out)
#define N4X (MM * D_MODEL / 4)        // 2097152
#define N4W (D_MODEL * D_MODEL / 4)   // 262144
__global__ __launch_bounds__(256) void cvt_all_kernel(const float* __restrict__ x,
                                                      const float* __restrict__ wq,
                                                      const float* __restrict__ wo,
                                                      u16* __restrict__ xb,
                                                      u16* __restrict__ wqb,
                                                      u16* __restrict__ wob) {
    int i = blockIdx.x * 256 + threadIdx.x;
    const float* s; u16* d; int off;
    if (i < N4X)            { s = x;  d = xb;  off = i; }
    else if (i < N4X + N4W) { s = wq; d = wqb; off = i - N4X; }
    else                    { s = wo; d = wob; off = i - N4X - N4W; }
    float4 f = ((const float4*)s)[off];
    u32 o[2] = { pkbf(f.x, f.y), pkbf(f.z, f.w) };
    ((uint2*)d)[off] = *(const uint2*)o;
}

// ================================================================ GEMM core (BK=64, XOR-swizzled LDS)
template <bool PERMUTE_OUT>
__device__ __forceinline__ void gemm_body(const u16* __restrict__ A,
                                          const u16* __restrict__ Bt,
                                          const float* __restrict__ Bo,
                                          u16* __restrict__ Cq, u16* __restrict__ CqT,
                                          float* __restrict__ Out)
{
    __shared__ __align__(16) u16 As[128*64];
    __shared__ __align__(16) u16 Bs[128*64];

    const int tid  = threadIdx.x;
    const int wave = tid >> 6;
    const int lane = tid & 63;
    const int quad = lane >> 4;
    const int l16  = lane & 15;
    const int bm = blockIdx.x >> 3;
    const int bn = blockIdx.x & 7;
    const int wm = wave >> 1, wn = wave & 1;

    f32x4 acc[4][4] = {};

    const int rp = tid >> 3;              // row in 32-row pass
    const int ch = tid & 7;               // physical chunk (8 elems)
    const int sc = ch ^ (rp & 7);         // source (logical) chunk

    const u16* Ab = A  + (size_t)(bm * 128 + rp) * D_MODEL + sc * 8;
    const u16* Bb = Bt + (size_t)(bn * 128 + rp) * D_MODEL + sc * 8;
    const int xr = l16 & 7;

    for (int k0 = 0; k0 < D_MODEL; k0 += 64) {
#pragma unroll
        for (int p = 0; p < 4; ++p) {
            __builtin_amdgcn_global_load_lds(
                (__attribute__((address_space(1))) void*)(Ab + (size_t)(32*p) * D_MODEL + k0),
                (__attribute__((address_space(3))) void*)(As + p*2048 + tid*8), 16, 0, 0);
            __builtin_amdgcn_global_load_lds(
                (__attribute__((address_space(1))) void*)(Bb + (size_t)(32*p) * D_MODEL + k0),
                (__attribute__((address_space(3))) void*)(Bs + p*2048 + tid*8), 16, 0, 0);
        }
        __syncthreads();

#pragma unroll
        for (int ks = 0; ks < 2; ++ks) {
            bf16x8 af[4], bfr[4];
#pragma unroll
            for (int t = 0; t < 4; ++t)
                af[t] = *(const bf16x8*)(const void*)(
                    As + (wm*64 + t*16 + l16)*64 + (((ks*4 + quad) ^ xr) * 8));
#pragma unroll
            for (int t = 0; t < 4; ++t)
                bfr[t] = *(const bf16x8*)(const void*)(
                    Bs + (wn*64 + t*16 + l16)*64 + (((ks*4 + quad) ^ xr) * 8));
#pragma unroll
            for (int i = 0; i < 4; ++i)
#pragma unroll
                for (int j = 0; j < 4; ++j)
                    acc[i][j] = __builtin_amdgcn_mfma_f32_16x16x32_bf16(af[i], bfr[j], acc[i][j], 0, 0, 0);
        }
        __syncthreads();
    }

    const int rowbase = bm*128 + wm*64;
    const int colbase = bn*128 + wn*64;
    if (PERMUTE_OUT) {
#pragma unroll
        for (int j = 0; j < 4; ++j) {
            const int col = colbase + j*16 + l16;
            const int h = col >> 6, dh = col & 63;
#pragma unroll
            for (int i = 0; i < 4; ++i) {
                const int row0 = rowbase + i*16 + quad*4;
                const int b = row0 >> 11, s0 = row0 & (SS - 1);
#pragma unroll
                for (int r = 0; r < 4; ++r)
                    Cq[(((size_t)(b*NH + h))*SS + s0 + r)*DHEAD + dh] = f2bf(acc[i][j][r]);
                u64 w = (u64)pkbf(acc[i][j][0], acc[i][j][1])
                      | ((u64)pkbf(acc[i][j][2], acc[i][j][3]) << 32);
                *(u64*)(CqT + ((size_t)((b*NH + h)*DHEAD + dh))*SS + s0) = w;
            }
        }
    } else {
#pragma unroll
        for (int j = 0; j < 4; ++j) {
            const int col = colbase + j*16 + l16;
            const float bias = Bo[col];
#pragma unroll
            for (int i = 0; i < 4; ++i) {
#pragma unroll
                for (int r = 0; r < 4; ++r) {
                    const int row = rowbase + i*16 + quad*4 + r;
                    Out[(size_t)row * D_MODEL + col] = acc[i][j][r] + bias;
                }
            }
        }
    }
}

__global__ __launch_bounds__(256) void gemm_qkv_kernel(const u16* __restrict__ A,
                                                       const u16* __restrict__ Bt,
                                                       u16* __restrict__ Cq,
                                                       u16* __restrict__ CqT) {
    gemm_body<true>(A, Bt, nullptr, Cq, CqT, nullptr);
}

__global__ __launch_bounds__(256) void gemm_out_kernel(const u16* __restrict__ A,
                                                       const u16* __restrict__ Bt,
                                                       const float* __restrict__ Bo,
                                                       float* __restrict__ Out) {
    gemm_body<false>(A, Bt, Bo, nullptr, nullptr, Out);
}

// ---------------------------------------------------------------- attention (Q=K=V), S^T formulation
// Wave owns 32 q-columns (was 64) -> grid 1024 blocks = 4 blocks/CU = 16 waves/CU.
// S^T = K*Q^T -> D holds 4 consecutive keys/lane -> b64 P writes, b128 P reads as PV B-frags.
// O^T = V^T * P^T. K/V double-buffered via swizzled DMA; one barrier per kt.
__global__ __launch_bounds__(256, 4) void attn_kernel(const u16* __restrict__ qkv,   // [B*H][2048][64]
                                                      const u16* __restrict__ qkvT,  // [B*H][64][2048]
                                                      u16* __restrict__ outb)        // [B][S][1024]
{
    __shared__ __align__(16) u16 Ks[2*2048];    // [buf][32 key][64 dh] chunk-swizzled
    __shared__ __align__(16) u16 Vt[2*2048];    // [buf][64 dh][32 key] chunk-swizzled
    __shared__ __align__(16) u16 Pl[4*1280];    // per-wave [32 q][keys], stride 40

    const int tid  = threadIdx.x;
    const int wave = tid >> 6;
    const int lane = tid & 63;
    const int quad = lane >> 4;
    const int l16  = lane & 15;

    const int bh   = blockIdx.x >> 4;
    const int qblk = blockIdx.x & 15;
    const int b = bh >> 4, h = bh & 15;
    const int qbase = qblk * 128 + wave * 32;

    const u16* Qp = qkv + (size_t)bh * SS * DHEAD;
    const float qscale = 0.125f * 1.4426950408889634f;  // 1/sqrt(64) * log2(e)

    // Q as B-operand frags: B[k=dh][n=q], lane reads 8 consecutive dh at fixed q
    bf16x8 qb[2][2];
#pragma unroll
    for (int nt = 0; nt < 2; ++nt)
#pragma unroll
        for (int ks = 0; ks < 2; ++ks) {
            U8 raw; raw.q = *(const uint4*)(Qp + (size_t)(qbase + nt*16 + l16)*DHEAD + ks*32 + quad*8);
            U8 w;
#pragma unroll
            for (int jj = 0; jj < 4; ++jj)
                ((u32*)&w)[jj] = pkbf(bf2f(raw.v[2*jj]) * qscale, bf2f(raw.v[2*jj+1]) * qscale);
            qb[nt][ks] = w.f;
        }

    // DMA staging sources (chunk-swizzled so frag reads are conflict-free)
    const int rK = tid >> 3, cK = (tid & 7) ^ ((rK >> 1) & 7);
    const u16* srcK = qkv  + (size_t)bh * SS * DHEAD + rK * DHEAD + cK * 8;
    const int rV = tid >> 2, cV = (tid & 3) ^ ((rV >> 1) & 3);
    const u16* srcV = qkvT + (size_t)bh * DHEAD * SS + (size_t)rV * SS + cV * 8;

    // frag read offsets
    const int h8 = (l16 >> 1) & 7, h4 = (l16 >> 1) & 3;
    const int ko0 = l16*64 + ((quad)     ^ h8) * 8;   // ks=0
    const int ko1 = l16*64 + ((4 + quad) ^ h8) * 8;   // ks=1
    const int vo  = l16*32 + ((quad) ^ h4) * 8;

    u16* Pw       = Pl + wave*1280 + l16*40 + quad*4;
    const u16* Pr = Pl + wave*1280 + l16*40 + quad*8;

    bf16x8 ones;
#pragma unroll
    for (int j = 0; j < 8; ++j) ones[j] = (__bf16)1.0f;

    f32x4 ot[4][2] = {};    // O^T[dh-tile][q-tile]
    f32x4 lsum[2]  = {};

    // prime buffer 0
    __builtin_amdgcn_global_load_lds(
        (__attribute__((address_space(1))) void*)(srcK),
        (__attribute__((address_space(3))) void*)(Ks + tid*8), 16, 0, 0);
    __builtin_amdgcn_global_load_lds(
        (__attribute__((address_space(1))) void*)(srcV),
        (__attribute__((address_space(3))) void*)(Vt + tid*8), 16, 0, 0);

#pragma unroll 2
    for (int kt = 0; kt < SS/32; ++kt) {
        __syncthreads();   // drains DMA for tile kt
        if (kt < SS/32 - 1) {   // prefetch kt+1 into other buffer (in flight during compute)
            __builtin_amdgcn_global_load_lds(
                (__attribute__((address_space(1))) void*)(srcK + (size_t)(kt+1)*32*DHEAD),
                (__attribute__((address_space(3))) void*)(Ks + ((kt+1)&1)*2048 + tid*8), 16, 0, 0);
            __builtin_amdgcn_global_load_lds(
                (__attribute__((address_space(1))) void*)(srcV + (kt+1)*32),
                (__attribute__((address_space(3))) void*)(Vt + ((kt+1)&1)*2048 + tid*8), 16, 0, 0);
        }
        const u16* Kb = Ks + (kt&1)*2048;
        const u16* Vb = Vt + (kt&1)*2048;

        // S^T = K * Q^T, then P^T = exp2(S^T) -> LDS (b64 packed writes)
#pragma unroll
        for (int mt = 0; mt < 2; ++mt) {
            f32x4 s[2] = {};
            bf16x8 kf0 = *(const bf16x8*)(const void*)(Kb + mt*1024 + ko0);
            bf16x8 kf1 = *(const bf16x8*)(const void*)(Kb + mt*1024 + ko1);
#pragma unroll
            for (int nt = 0; nt < 2; ++nt)
                s[nt] = __builtin_amdgcn_mfma_f32_16x16x32_bf16(kf0, qb[nt][0], s[nt], 0, 0, 0);
#pragma unroll
            for (int nt = 0; nt < 2; ++nt)
                s[nt] = __builtin_amdgcn_mfma_f32_16x16x32_bf16(kf1, qb[nt][1], s[nt], 0, 0, 0);
#pragma unroll
            for (int nt = 0; nt < 2; ++nt) {
                float p0 = __builtin_amdgcn_exp2f(s[nt][0]);
                float p1 = __builtin_amdgcn_exp2f(s[nt][1]);
                float p2 = __builtin_amdgcn_exp2f(s[nt][2]);
                float p3 = __builtin_amdgcn_exp2f(s[nt][3]);
                u64 w = (u64)pkbf(p0, p1) | ((u64)pkbf(p2, p3) << 32);
                *(u64*)(Pw + nt*640 + mt*16) = w;
            }
        }

        // P^T frags (B-operand: 8 consecutive keys at fixed q) + V^T frags (A-operand)
        bf16x8 pf[2];
#pragma unroll
        for (int nt = 0; nt < 2; ++nt)
            pf[nt] = *(const bf16x8*)(const void*)(Pr + nt*640);
#pragma unroll
        for (int nt = 0; nt < 2; ++nt)
            lsum[nt] = __builtin_amdgcn_mfma_f32_16x16x32_bf16(ones, pf[nt], lsum[nt], 0, 0, 0);
        bf16x8 vf[4];
#pragma unroll
        for (int dt = 0; dt < 4; ++dt)
            vf[dt] = *(const bf16x8*)(const void*)(Vb + dt*512 + vo);
#pragma unroll
        for (int dt = 0; dt < 4; ++dt)
#pragma unroll
            for (int nt = 0; nt < 2; ++nt)
                ot[dt][nt] = __builtin_amdgcn_mfma_f32_16x16x32_bf16(vf[dt], pf[nt], ot[dt][nt], 0, 0, 0);
    }

    // epilogue: O = O^T / lsum, packed 8B stores (4 consecutive dh per lane)
    float inv[2];
#pragma unroll
    for (int nt = 0; nt < 2; ++nt) inv[nt] = 1.0f / lsum[nt][0];
#pragma unroll
    for (int dt = 0; dt < 4; ++dt)
#pragma unroll
        for (int nt = 0; nt < 2; ++nt) {
            u64 w = (u64)pkbf(ot[dt][nt][0]*inv[nt], ot[dt][nt][1]*inv[nt])
                  | ((u64)pkbf(ot[dt][nt][2]*inv[nt], ot[dt][nt][3]*inv[nt]) << 32);
            *(u64*)(outb + ((size_t)(b*SS + qbase + nt*16 + l16))*D_MODEL
                         + h*64 + dt*16 + quad*4) = w;
        }
}

// ---------------------------------------------------------------- launcher
extern "C" void kernel_launch(void* const* d_in, const int* in_sizes, int n_in,
                              void* d_out, int out_size, void* d_ws, size_t ws_size,
                              hipStream_t stream)
{
    (void)in_sizes; (void)n_in; (void)out_size; (void)ws_size;
    const float* x  = (const float*)d_in[0];
    const float* wq = (const float*)d_in[1];
    const float* wo = (const float*)d_in[2];
    const float* bo = (const float*)d_in[3];

    char* ws = (char*)d_ws;
    u16* xb    = (u16*)(ws);                          // 16 MiB  [8192][1024] bf16 x
    u16* wqb   = (u16*)(ws + (size_t)(16 << 20));     //  2 MiB
    u16* wob   = (u16*)(ws + (size_t)(18 << 20));     //  2 MiB
    u16* qkvb  = (u16*)(ws + (size_t)(20 << 20));     // 16 MiB  [64][2048][64]
    u16* qkvTb = (u16*)(ws + (size_t)(36 << 20));     // 16 MiB  [64][64][2048]
    u16* attb  = xb;                                  // reuse x-bf16 buffer for attention output

    cvt_all_kernel<<<(N4X + 2*N4W) / 256, 256, 0, stream>>>(x, wq, wo, xb, wqb, wob);
    gemm_qkv_kernel<<<(MM/128) * (D_MODEL/128), 256, 0, stream>>>(xb, wqb, qkvb, qkvTb);
    attn_kernel<<<BB * NH * (SS/128), 256, 0, stream>>>(qkvb, qkvTb, attb);
    gemm_out_kernel<<<(MM/128) * (D_MODEL/128), 256, 0, stream>>>(attb, wob, bo, (float*)d_out);
}